// Round 7
// baseline (1126.444 us; speedup 1.0000x reference)
//
#include <hip/hip_runtime.h>

#define HW 4096  // 64*64 spatial

#if __has_builtin(__builtin_amdgcn_exp2f)
#define QSCALE 1.4426950408889634f            // prescale q by log2(e); exp2 is native v_exp_f32
__device__ __forceinline__ float fexp(float l) { return __builtin_amdgcn_exp2f(l); }
#else
#define QSCALE 1.0f
__device__ __forceinline__ float fexp(float l) { return __expf(l); }
#endif

// R14: fused, GEMM feed rebuilt for issue rate. R13 (98us, VALUBusy 29%) was
// starved by its own GEMM feed: column-per-lane forced 320 scalar b32 x-loads
// per thread (~20k+ cyc VMEM issue per CU) plus 48 LDS weight broadcasts per
// chunk. Fix: (a) GEMM thread = (halo row, w-quad) -> x loads are float4
// (4x fewer VMEM instrs, coalesced); (b) weights read as lane-uniform global
// float4 -> L1 broadcast (768 B/block, no LDS unit, no scalar cache — the
// R8/R10 trap); (c) single-o blocks: LDS 29.5 KB = kv+qs -> 4 blocks/CU,
// 8 waves/SIMD at lb(512,8) (2x R13 TLP). GEMM liveness ~46 regs, attn ~45:
// fits 64-VGPR cap without spill. GEMM and attention mappings are fully
// decoupled (k/v/q route through LDS).
// TCC FETCH/WRITE attribution is suspect (R13: 165 MB WRITE with zero device
// globals, WRITE~2xFETCH in every round) — steering by dur_us.
//
// Block = (b, o, half): grid 1024 = 8b x 64o x 2half, 512 threads.
// b = blockIdx&7 -> XCD-pinned: each XCD reads only x[b] (1 MB, L2-resident).
// Phase 1 GEMM: thread (rq = t>>4, quad = (t&15)*4) accumulates q/k/v for
//   halo row rq, pixel cols quad..quad+3 over 64 channels; rows 32..37 by a
//   second pass for t<96 (waves 0-1). OOB rows contribute zeros (pad
//   semantics: zero-pad + 1x1 conv => k=v=0 outside).
// Phase 2 attention (R13-verified): warp j owns pixel rows 4j..4j+3, lane =
//   col; taps kv[4j+hrl][lane+dc] = 64 consecutive dwords/wave = conflict-
//   free; 196 exp/thread; sched_barrier caps liveness per halo row.
// rel_w/rel_h dead (constant along the 49-entry softmax axis).
// k at kv[r][0..69] (halo cols -3..66 -> +3), v at +70: ds_read2_b32 pairs.
__global__ __launch_bounds__(512, 8) void fused_attn(
    const float* __restrict__ x,
    const float* __restrict__ wq,
    const float* __restrict__ wk,
    const float* __restrict__ wv,
    float* __restrict__ out)
{
    __shared__ float kv[38][140];     // 21.3 KB
    __shared__ float qs[32][64];      // 8 KB  (q * QSCALE)

    const int t  = threadIdx.x;
    const int b  = blockIdx.x & 7;                 // XCD pin
    const int o  = (blockIdx.x >> 3) & 63;
    const int R0 = (blockIdx.x >> 9) * 32;         // row-half base

    // ---- zero the 3-col halo pads (cols 0..2,67..69 of k; +70 for v) ----
    for (int i = t; i < 38 * 12; i += 512) {
        const int r = i / 12, u = i % 12;
        const int part = u / 6, uu = u % 6;
        kv[r][part * 70 + (uu < 3 ? uu : uu + 64)] = 0.f;
    }

    const float* __restrict__ wqp = wq + o * 64;   // 256 B each, L1-broadcast
    const float* __restrict__ wkp = wk + o * 64;
    const float* __restrict__ wvp = wv + o * 64;
    const float* __restrict__ xb  = x + (size_t)b * 64 * HW;

    const int wq4 = (t & 15) << 2;                 // pixel-col quad base

    // One GEMM pass for halo row rq: float4 x feed, lane-uniform float4 W.
    auto gemm_row = [&](const int rq) {
        const int  grm = R0 + rq - 3;              // global image row
        const bool mv  = (unsigned)grm < 64u;
        const float* __restrict__ xp = xb + (size_t)(mv ? grm : 0) * 64 + wq4;
        float qa[4] = {0.f,0.f,0.f,0.f}, ka[4] = {0.f,0.f,0.f,0.f},
              va[4] = {0.f,0.f,0.f,0.f};
        #pragma unroll
        for (int c0 = 0; c0 < 64; c0 += 4) {
            const float4 wqv = *(const float4*)&wqp[c0];   // uniform -> L1 hit
            const float4 wkv = *(const float4*)&wkp[c0];
            const float4 wvv = *(const float4*)&wvp[c0];
            const float wqa[4] = {wqv.x, wqv.y, wqv.z, wqv.w};
            const float wka[4] = {wkv.x, wkv.y, wkv.z, wkv.w};
            const float wva[4] = {wvv.x, wvv.y, wvv.z, wvv.w};
            #pragma unroll
            for (int cc = 0; cc < 4; ++cc) {
                float4 xv = {0.f, 0.f, 0.f, 0.f};
                if (mv) xv = *(const float4*)&xp[(size_t)(c0 + cc) * HW];
                qa[0] = fmaf(wqa[cc], xv.x, qa[0]);
                qa[1] = fmaf(wqa[cc], xv.y, qa[1]);
                qa[2] = fmaf(wqa[cc], xv.z, qa[2]);
                qa[3] = fmaf(wqa[cc], xv.w, qa[3]);
                ka[0] = fmaf(wka[cc], xv.x, ka[0]);
                ka[1] = fmaf(wka[cc], xv.y, ka[1]);
                ka[2] = fmaf(wka[cc], xv.z, ka[2]);
                ka[3] = fmaf(wka[cc], xv.w, ka[3]);
                va[0] = fmaf(wva[cc], xv.x, va[0]);
                va[1] = fmaf(wva[cc], xv.y, va[1]);
                va[2] = fmaf(wva[cc], xv.z, va[2]);
                va[3] = fmaf(wva[cc], xv.w, va[3]);
            }
        }
        // commit k/v (zeros for OOB rows = pad semantics) and q (pixel rows)
        #pragma unroll
        for (int i2 = 0; i2 < 4; ++i2) {
            kv[rq][3  + wq4 + i2] = ka[i2];        // ds_write2 pairs
            kv[rq][73 + wq4 + i2] = va[i2];
        }
        if (rq >= 3 && rq <= 34) {
            float4 qv = { qa[0] * QSCALE, qa[1] * QSCALE,
                          qa[2] * QSCALE, qa[3] * QSCALE };
            *(float4*)&qs[rq - 3][wq4] = qv;       // aligned b128
        }
    };

    gemm_row(t >> 4);                              // rows 0..31
    if (t < 96) gemm_row(32 + (t >> 4));           // rows 32..37 (waves 0-1)

    __syncthreads();

    // ---- attention (R13-verified conflict-free mapping) ----
    const int lane = t & 63;          // pixel column
    const int j    = t >> 6;          // warp 0..7 -> pixel rows 4j..4j+3

    float qv4[4], den[4], num[4];
    #pragma unroll
    for (int i = 0; i < 4; ++i) {
        qv4[i] = qs[4 * j + i][lane];              // row-uniform, 64 consec
        den[i] = 0.f; num[i] = 0.f;
    }

    // pixel row p=4j+i taps halo rows p..p+6 -> kv rows 4j..4j+9
    #pragma unroll
    for (int hrl = 0; hrl < 10; ++hrl) {
        float kk[7], vv[7];
        #pragma unroll
        for (int dc = 0; dc < 7; ++dc) {
            kk[dc] = kv[4 * j + hrl][lane + dc];          // ds_read2 pair
            vv[dc] = kv[4 * j + hrl][70 + lane + dc];
        }
        #pragma unroll
        for (int dc = 0; dc < 7; ++dc) {
            #pragma unroll
            for (int i = 0; i < 4; ++i) {
                if (hrl - i >= 0 && hrl - i < 7) {        // compile-time
                    float e = fexp(qv4[i] * kk[dc]);
                    den[i] += e;
                    num[i] = fmaf(e, vv[dc], num[i]);
                }
            }
        }
        __builtin_amdgcn_sched_barrier(0);                // cap liveness
    }

    float* __restrict__ ob = out + ((size_t)(b * 64 + o)) * HW;
    #pragma unroll
    for (int i = 0; i < 4; ++i)
        ob[(size_t)(R0 + 4 * j + i) * 64 + lane] = num[i] / den[i];
}

extern "C" void kernel_launch(void* const* d_in, const int* in_sizes, int n_in,
                              void* d_out, int out_size, void* d_ws, size_t ws_size,
                              hipStream_t stream)
{
    // d_in: 0=x, 1=wq, 2=wk, 3=wv (fp32), 4=rel_w, 5=rel_h (dead: softmax
    // shift-invariance), 6=kernel_size(7), 7=padding(3) hardcoded.
    fused_attn<<<dim3(1024), dim3(512), 0, stream>>>(
        (const float*)d_in[0], (const float*)d_in[1],
        (const float*)d_in[2], (const float*)d_in[3],
        (float*)d_out);
}